// Round 8
// baseline (1697.208 us; speedup 1.0000x reference)
//
#include <hip/hip_runtime.h>
#include <math.h>

#define N_NODES 50000
#define E_EDGES 320000
#define DIN_    768
#define D_      256
#define R_TYPES 4
#define L_LAYERS 3
#define BATCH_  64
#define T_STEPS 6
#define SD_     128
#define SH_     256
#define NC_     14
#define ALPHA_  0.15f
#define NBLK_B  1250   // bucketing blocks: 1250*256 == E_EDGES exactly
#define POOL_CHUNK 256
#define E_PAD   (E_EDGES + 256)   // padded edge capacity (4 buckets padded to %64)
#define SCAN_BLK 49               // 49*1024 >= N_NODES
#define NCAT    (D_ + R_TYPES * D_)   // 1280

typedef __bf16 bf16_t;
typedef bf16_t bf16x8_t __attribute__((ext_vector_type(8)));
typedef bf16_t bf16x4_t __attribute__((ext_vector_type(4)));
typedef float  f32x4_t  __attribute__((ext_vector_type(4)));

__device__ __forceinline__ f32x4_t mfma16(bf16x8_t a, bf16x8_t b, f32x4_t c) {
    return __builtin_amdgcn_mfma_f32_16x16x32_bf16(a, b, c, 0, 0, 0);
}

// ---------------- fp32 -> bf16 conversion (vector4, n % 4 == 0)
__global__ void f2b_kernel(const float* __restrict__ src, bf16_t* __restrict__ dst, int n4)
{
    for (int i = blockIdx.x * blockDim.x + threadIdx.x; i < n4; i += gridDim.x * blockDim.x) {
        float4 v = ((const float4*)src)[i];
        bf16_t o[4] = {(bf16_t)v.x, (bf16_t)v.y, (bf16_t)v.z, (bf16_t)v.w};
        *(ulong1*)&dst[i * 4] = *(ulong1*)o;
    }
}

// ---------------- pack Wcat[l] = [Ws[l] (256 rows) | Wr[l][0..3] (1024 rows)] as bf16
__global__ void pack_wcat_kernel(const float* __restrict__ Ws, const float* __restrict__ Wr,
                                 bf16_t* __restrict__ Wcat)
{
    int total = L_LAYERS * NCAT * D_;
    for (int i = blockIdx.x * blockDim.x + threadIdx.x; i < total; i += gridDim.x * blockDim.x) {
        int l = i / (NCAT * D_);
        int rem = i - l * NCAT * D_;
        int row = rem / D_, k = rem - row * D_;
        float v = (row < D_) ? Ws[((size_t)l * D_ + row) * D_ + k]
                             : Wr[((size_t)l * R_TYPES * D_ + (row - D_)) * D_ + k];
        Wcat[i] = (bf16_t)v;
    }
}

// ---------------- [2][R][C] -> [2][C][R] transpose (small weights)
__global__ void transpose2_kernel(const float* __restrict__ in, float* __restrict__ out, int R, int C)
{
    int total = 2 * R * C;
    for (int i = blockIdx.x * blockDim.x + threadIdx.x; i < total; i += gridDim.x * blockDim.x) {
        int dir = i / (R * C);
        int rem = i - dir * R * C;
        int r = rem / C, c = rem - r * C;
        out[dir * R * C + c * R + r] = in[i];
    }
}

// ---------------- proj GEMM v2: 64 rows x 128 cols per block, grid (MB, 2).
// x fp32 converted during staging; x read <=2x (2nd pass mostly L3 hits).
// Wave (wy,wx): rows wy*32..+32, cols wx*64..+64 -> acc[2][4].
__global__ __launch_bounds__(256) void proj_mfma2(
    const float* __restrict__ A, const bf16_t* __restrict__ W,
    const float* __restrict__ bias, float* __restrict__ outf,
    bf16_t* __restrict__ outb, int M)
{
    __shared__ bf16_t As[64][44];
    __shared__ bf16_t Bs[128][44];
    const int m0 = blockIdx.x * 64;
    const int n0 = blockIdx.y * 128;
    const int tid = threadIdx.x;
    const int wave = tid >> 6, lane = tid & 63;
    const int wy = wave >> 1, wx = wave & 1;
    const int q = lane >> 4, c = lane & 15;
    const int srow = tid >> 2, skq = tid & 3;

    f32x4_t acc[2][4] = {};
    for (int k0 = 0; k0 < DIN_; k0 += 32) {
        {
            int m = m0 + srow;
            bf16_t tmp[8] = {};
            if (m < M) {
                float4 v0 = *(const float4*)&A[(size_t)m * DIN_ + k0 + skq * 8];
                float4 v1 = *(const float4*)&A[(size_t)m * DIN_ + k0 + skq * 8 + 4];
                tmp[0] = (bf16_t)v0.x; tmp[1] = (bf16_t)v0.y; tmp[2] = (bf16_t)v0.z; tmp[3] = (bf16_t)v0.w;
                tmp[4] = (bf16_t)v1.x; tmp[5] = (bf16_t)v1.y; tmp[6] = (bf16_t)v1.z; tmp[7] = (bf16_t)v1.w;
            }
            *(bf16x8_t*)&As[srow][skq * 8] = *(bf16x8_t*)tmp;
            #pragma unroll
            for (int s = 0; s < 2; s++) {
                int slot = tid + s * 256;
                int nrow = slot >> 2, nkq = slot & 3;
                *(bf16x8_t*)&Bs[nrow][nkq * 8] = *(const bf16x8_t*)&W[(size_t)(n0 + nrow) * DIN_ + k0 + nkq * 8];
            }
        }
        __syncthreads();
        bf16x8_t af[2], bfv[4];
        #pragma unroll
        for (int mt = 0; mt < 2; mt++) af[mt] = *(const bf16x8_t*)&As[wy * 32 + mt * 16 + c][q * 8];
        #pragma unroll
        for (int nt = 0; nt < 4; nt++) bfv[nt] = *(const bf16x8_t*)&Bs[wx * 64 + nt * 16 + c][q * 8];
        #pragma unroll
        for (int mt = 0; mt < 2; mt++)
            #pragma unroll
            for (int nt = 0; nt < 4; nt++)
                acc[mt][nt] = mfma16(af[mt], bfv[nt], acc[mt][nt]);
        __syncthreads();
    }
    #pragma unroll
    for (int nt = 0; nt < 4; nt++) {
        int n = n0 + wx * 64 + nt * 16 + c;
        float bv = bias[n];
        #pragma unroll
        for (int mt = 0; mt < 2; mt++) {
            #pragma unroll
            for (int j = 0; j < 4; j++) {
                int m = m0 + wy * 32 + mt * 16 + q * 4 + j;
                if (m < M) {
                    float v = acc[mt][nt][j] + bv;
                    outf[(size_t)m * D_ + n] = v;
                    outb[(size_t)m * D_ + n] = (bf16_t)v;
                }
            }
        }
    }
}

// ---------------- dual GEMM v2: [accb | txAll] = hbb @ Wcat[l].T ; K=256, N=1280.
// 64x128 tile, grid (MB, 10). n<256 -> accb fp32 (+bias); else txAll bf16.
__global__ __launch_bounds__(256) void linear_dual_mfma2(
    const bf16_t* __restrict__ A, const bf16_t* __restrict__ W,
    const float* __restrict__ bias, float* __restrict__ outf,
    bf16_t* __restrict__ outb, int M)
{
    __shared__ bf16_t As[64][44];
    __shared__ bf16_t Bs[128][44];
    const int m0 = blockIdx.x * 64;
    const int n0 = blockIdx.y * 128;
    const int tid = threadIdx.x;
    const int wave = tid >> 6, lane = tid & 63;
    const int wy = wave >> 1, wx = wave & 1;
    const int q = lane >> 4, c = lane & 15;
    const int srow = tid >> 2, skq = tid & 3;

    f32x4_t acc[2][4] = {};
    for (int k0 = 0; k0 < D_; k0 += 32) {
        {
            int m = m0 + srow;
            bf16x8_t av = {};
            if (m < M) av = *(const bf16x8_t*)&A[(size_t)m * D_ + k0 + skq * 8];
            *(bf16x8_t*)&As[srow][skq * 8] = av;
            #pragma unroll
            for (int s = 0; s < 2; s++) {
                int slot = tid + s * 256;
                int nrow = slot >> 2, nkq = slot & 3;
                *(bf16x8_t*)&Bs[nrow][nkq * 8] = *(const bf16x8_t*)&W[(size_t)(n0 + nrow) * D_ + k0 + nkq * 8];
            }
        }
        __syncthreads();
        bf16x8_t af[2], bfv[4];
        #pragma unroll
        for (int mt = 0; mt < 2; mt++) af[mt] = *(const bf16x8_t*)&As[wy * 32 + mt * 16 + c][q * 8];
        #pragma unroll
        for (int nt = 0; nt < 4; nt++) bfv[nt] = *(const bf16x8_t*)&Bs[wx * 64 + nt * 16 + c][q * 8];
        #pragma unroll
        for (int mt = 0; mt < 2; mt++)
            #pragma unroll
            for (int nt = 0; nt < 4; nt++)
                acc[mt][nt] = mfma16(af[mt], bfv[nt], acc[mt][nt]);
        __syncthreads();
    }
    #pragma unroll
    for (int nt = 0; nt < 4; nt++) {
        int n = n0 + wx * 64 + nt * 16 + c;
        float bv = (n < D_) ? bias[n] : 0.0f;
        #pragma unroll
        for (int mt = 0; mt < 2; mt++) {
            #pragma unroll
            for (int j = 0; j < 4; j++) {
                int m = m0 + wy * 32 + mt * 16 + q * 4 + j;
                if (m < M) {
                    float v = acc[mt][nt][j] + bv;
                    if (n < D_) outf[(size_t)m * D_ + n] = v;
                    else        outb[(size_t)m * (R_TYPES * D_) + (n - D_)] = (bf16_t)v;
                }
            }
        }
    }
}

// ---------------- edge bucketing by type: deterministic 3-phase, zero global atomics
__global__ __launch_bounds__(256) void bucket_count2(const int* __restrict__ et,
                                                     int* __restrict__ blockCnt)
{
    int b = blockIdx.x, tid = threadIdx.x;
    int r = et[b * 256 + tid];
    int lane = tid & 63, wv = tid >> 6;
    __shared__ int wcnt[4][4];
    #pragma unroll
    for (int t = 0; t < 4; t++) {
        unsigned long long m = __ballot(r == t);
        if (lane == 0) wcnt[wv][t] = __popcll(m);
    }
    __syncthreads();
    if (tid < 4)
        blockCnt[b * 4 + tid] = wcnt[0][tid] + wcnt[1][tid] + wcnt[2][tid] + wcnt[3][tid];
}

__global__ void bucket_scan(const int* __restrict__ blockCnt, int* __restrict__ boffP,
                            int* __restrict__ cnt, int* __restrict__ basePerBlock,
                            int* __restrict__ bsrc, int* __restrict__ bdst)
{
    __shared__ int tot[4];
    int t = threadIdx.x;
    if (t < 4) {
        int s = 0;
        for (int b = 0; b < NBLK_B; b++) s += blockCnt[b * 4 + t];
        tot[t] = s;
    }
    __syncthreads();
    if (t == 0) {
        int o = 0;
        for (int r = 0; r < 4; r++) {
            boffP[r] = o; cnt[r] = tot[r];
            o += (tot[r] + 63) & ~63;
        }
        boffP[4] = o;
    }
    __syncthreads();
    if (t < 4) {
        int run = boffP[t];
        for (int b = 0; b < NBLK_B; b++) { basePerBlock[b * 4 + t] = run; run += blockCnt[b * 4 + t]; }
    }
    __syncthreads();
    for (int r = 0; r < 4; r++) {
        int s = boffP[r] + cnt[r], e = boffP[r + 1];
        for (int i = s + t; i < e; i += 64) { bsrc[i] = 0; bdst[i] = 0; }
    }
}

__global__ __launch_bounds__(256) void bucket_scatter2(
    const int* __restrict__ ei, const int* __restrict__ et,
    const int* __restrict__ basePerBlock, int* __restrict__ bsrc, int* __restrict__ bdst)
{
    int b = blockIdx.x, tid = threadIdx.x;
    int e = b * 256 + tid;
    int r = et[e];
    int lane = tid & 63, wv = tid >> 6;
    __shared__ int wcnt[4][4];
    int myrank = 0;
    unsigned long long ltmask = (1ull << lane) - 1ull;
    #pragma unroll
    for (int t = 0; t < 4; t++) {
        unsigned long long m = __ballot(r == t);
        if (r == t) myrank = __popcll(m & ltmask);
        if (lane == 0) wcnt[wv][t] = __popcll(m);
    }
    __syncthreads();
    int wbase = 0;
    for (int w = 0; w < wv; w++) wbase += wcnt[w][r];
    int pos = basePerBlock[b * 4 + r] + wbase + myrank;
    bsrc[pos] = ei[e];
    bdst[pos] = ei[E_EDGES + e];
}

__global__ void embmean_kernel(const float* __restrict__ emb, float* __restrict__ em)
{
    int lr = threadIdx.x;
    if (lr < L_LAYERS * R_TYPES) {
        float s = 0.0f;
        for (int k = 0; k < 64; k++) s += emb[lr * 64 + k];
        em[lr] = s / 64.0f;
    }
}

// ---------------- CSR-by-dst build
__global__ __launch_bounds__(256) void deg_count_kernel(
    const int* __restrict__ bdst, const int* __restrict__ boffP, const int* __restrict__ cnt,
    int* __restrict__ deg)
{
    __shared__ int sb[5], sc[4];
    if (threadIdx.x < 5) sb[threadIdx.x] = boffP[threadIdx.x];
    if (threadIdx.x < 4) sc[threadIdx.x] = cnt[threadIdx.x];
    __syncthreads();
    int total = sb[4];
    for (int p = blockIdx.x * blockDim.x + threadIdx.x; p < total; p += gridDim.x * blockDim.x) {
        int r = 0; while (r < 3 && p >= sb[r + 1]) r++;
        if (p - sb[r] < sc[r]) atomicAdd(&deg[bdst[p]], 1);
    }
}

__global__ __launch_bounds__(256) void scan1_kernel(const int* __restrict__ deg,
                                                    int* __restrict__ rowptr, int* __restrict__ blockSum)
{
    __shared__ int sdata[256];
    int b = blockIdx.x, t = threadIdx.x;
    int idx0 = b * 1024 + t * 4;
    int d[4];
    #pragma unroll
    for (int j = 0; j < 4; j++) d[j] = (idx0 + j < N_NODES) ? deg[idx0 + j] : 0;
    int tsum = d[0] + d[1] + d[2] + d[3];
    sdata[t] = tsum;
    __syncthreads();
    for (int off = 1; off < 256; off <<= 1) {
        int v = (t >= off) ? sdata[t - off] : 0;
        __syncthreads();
        sdata[t] += v;
        __syncthreads();
    }
    int ex = sdata[t] - tsum;
    int acc = ex;
    #pragma unroll
    for (int j = 0; j < 4; j++) {
        if (idx0 + j < N_NODES) rowptr[idx0 + j] = acc;
        acc += d[j];
    }
    if (t == 255) blockSum[b] = sdata[255];
}

__global__ void scan2_kernel(const int* __restrict__ blockSum, int* __restrict__ blockOff)
{
    if (threadIdx.x == 0) {
        int o = 0;
        for (int b = 0; b < SCAN_BLK; b++) { blockOff[b] = o; o += blockSum[b]; }
    }
}

__global__ __launch_bounds__(256) void scan3_kernel(int* __restrict__ rowptr,
                                                    const int* __restrict__ blockOff,
                                                    int* __restrict__ cursor)
{
    int idx = blockIdx.x * blockDim.x + threadIdx.x;
    if (idx < N_NODES) {
        int v = rowptr[idx] + blockOff[idx >> 10];
        rowptr[idx] = v; cursor[idx] = v;
    }
    if (idx == 0) rowptr[N_NODES] = E_EDGES;
}

__global__ __launch_bounds__(256) void csr_scatter_kernel(
    const int* __restrict__ bsrc, const int* __restrict__ bdst,
    const int* __restrict__ boffP, const int* __restrict__ cnt,
    int* __restrict__ cursor, int* __restrict__ csrSrc, int* __restrict__ csrPos)
{
    __shared__ int sb[5], sc[4];
    if (threadIdx.x < 5) sb[threadIdx.x] = boffP[threadIdx.x];
    if (threadIdx.x < 4) sc[threadIdx.x] = cnt[threadIdx.x];
    __syncthreads();
    int total = sb[4];
    for (int p = blockIdx.x * blockDim.x + threadIdx.x; p < total; p += gridDim.x * blockDim.x) {
        int r = 0; while (r < 3 && p >= sb[r + 1]) r++;
        if (p - sb[r] < sc[r]) {
            int pos = atomicAdd(&cursor[bdst[p]], 1);
            csrSrc[pos] = bsrc[p];
            csrPos[pos] = p;
        }
    }
}

// ---------------- MFMA attention score, ALL types in one launch (padded buckets).
__global__ __launch_bounds__(256) void attn_mfma(
    const bf16_t* __restrict__ hb, const int* __restrict__ bsrc, const int* __restrict__ bdst,
    const int* __restrict__ boffP, const int* __restrict__ cnt, int l,
    const bf16_t* __restrict__ W1base, const float* __restrict__ b1base,
    const float* __restrict__ W2base, const float* __restrict__ b2base,
    const float* __restrict__ em, float* __restrict__ sbuf)
{
    const int p0 = blockIdx.x * 64;
    if (p0 >= boffP[4]) return;
    int r = 0;
    while (r < 3 && p0 >= boffP[r + 1]) r++;
    const int lr = l * R_TYPES + r;
    const int base = boffP[r];
    const int cnt_r = cnt[r];
    const bf16_t* W1 = W1base + (size_t)lr * 128 * 512;
    const float*  b1 = b1base + lr * 128;
    const float*  W2 = W2base + lr * 128;

    __shared__ int nd_d[64], nd_s[64];
    __shared__ bf16_t Acat[64][44];
    __shared__ bf16_t Bs[128][44];
    const int tid = threadIdx.x;
    if (tid < 64) nd_d[tid] = bdst[p0 + tid];
    else if (tid < 128) nd_s[tid - 64] = bsrc[p0 + tid - 64];
    __syncthreads();
    const int wave = tid >> 6, lane = tid & 63;
    const int q = lane >> 4, c = lane & 15;
    const int srow = tid >> 2, skq = tid & 3;

    f32x4_t acc[8] = {};
    for (int ks = 0; ks < 16; ks++) {
        {
            int node = (ks < 8) ? nd_d[srow] : nd_s[srow];
            int koffm = (ks & 7) * 32 + skq * 8;
            *(bf16x8_t*)&Acat[srow][skq * 8] = *(const bf16x8_t*)&hb[(size_t)node * D_ + koffm];
            #pragma unroll
            for (int s = 0; s < 2; s++) {
                int slot = tid + s * 256;
                int nrow = slot >> 2, nkq = slot & 3;
                *(bf16x8_t*)&Bs[nrow][nkq * 8] = *(const bf16x8_t*)&W1[(size_t)nrow * 512 + ks * 32 + nkq * 8];
            }
        }
        __syncthreads();
        bf16x8_t af = *(const bf16x8_t*)&Acat[wave * 16 + c][q * 8];
        #pragma unroll
        for (int nt = 0; nt < 8; nt++) {
            bf16x8_t bfv = *(const bf16x8_t*)&Bs[nt * 16 + c][q * 8];
            acc[nt] = mfma16(af, bfv, acc[nt]);
        }
        __syncthreads();
    }
    float part[4] = {0, 0, 0, 0};
    #pragma unroll
    for (int nt = 0; nt < 8; nt++) {
        int n = nt * 16 + c;
        float b1v = b1[n], w2v = W2[n];
        #pragma unroll
        for (int j = 0; j < 4; j++) {
            float v = acc[nt][j] + b1v;
            v = v > 0.0f ? v : 0.0f;
            part[j] += v * w2v;
        }
    }
    #pragma unroll
    for (int j = 0; j < 4; j++) {
        #pragma unroll
        for (int mask = 1; mask <= 8; mask <<= 1)
            part[j] += __shfl_xor(part[j], mask);
    }
    if (c == 0) {
        float b2v = b2base[lr], emv = em[lr];
        #pragma unroll
        for (int j = 0; j < 4; j++) {
            int p = p0 + wave * 16 + q * 4 + j;
            bool valid = (p - base) < cnt_r;
            float sv = part[j] + b2v;
            sv = sv > 0.0f ? sv : 0.2f * sv;   // leaky_relu(0.2)
            sbuf[p] = valid ? (sv + emv) : -1e30f;
        }
    }
}

// ---------------- masked-softmax helpers
__device__ __forceinline__ unsigned fkey(float f) {
    unsigned u = __float_as_uint(f);
    return (u & 0x80000000u) ? ~u : (u | 0x80000000u);
}
__device__ __forceinline__ float fkey_inv(unsigned k) {
    unsigned u = (k & 0x80000000u) ? (k ^ 0x80000000u) : ~k;
    return __uint_as_float(u);
}

// grid = (256, 4): blockIdx.y = type. redl = red + l*8.
__global__ void bucket_max_kernel(const float* __restrict__ sbuf, const int* __restrict__ boffP,
                                  unsigned* __restrict__ redl)
{
    int r = blockIdx.y;
    int lo = boffP[r], hi = boffP[r + 1];
    float m = -1e30f;
    for (int i = lo + blockIdx.x * blockDim.x + threadIdx.x; i < hi; i += gridDim.x * blockDim.x)
        m = fmaxf(m, sbuf[i]);
    for (int o = 32; o; o >>= 1) m = fmaxf(m, __shfl_down(m, o));
    __shared__ float wm[4];
    int lane = threadIdx.x & 63, wv = threadIdx.x >> 6;
    if (lane == 0) wm[wv] = m;
    __syncthreads();
    if (threadIdx.x == 0) {
        float b = fmaxf(fmaxf(wm[0], wm[1]), fmaxf(wm[2], wm[3]));
        atomicMax(&redl[r * 2], fkey(b));
    }
}

__global__ void bucket_sum_kernel(const float* __restrict__ sbuf, const int* __restrict__ boffP,
                                  unsigned* __restrict__ redl)
{
    int r = blockIdx.y;
    int lo = boffP[r], hi = boffP[r + 1];
    float mxf = fkey_inv(redl[r * 2]);
    float s = 0.0f;
    for (int i = lo + blockIdx.x * blockDim.x + threadIdx.x; i < hi; i += gridDim.x * blockDim.x)
        s += expf(sbuf[i] - mxf);
    for (int o = 32; o; o >>= 1) s += __shfl_down(s, o);
    __shared__ float wm[4];
    int lane = threadIdx.x & 63, wv = threadIdx.x >> 6;
    if (lane == 0) wm[wv] = s;
    __syncthreads();
    if (threadIdx.x == 0) atomicAdd((float*)&redl[r * 2 + 1], wm[0] + wm[1] + wm[2] + wm[3]);
}

// ---------------- FUSED message-gather + residual + LayerNorm + GELU.
__global__ __launch_bounds__(256) void msg_ln_gelu_kernel(
    const float* __restrict__ sbuf, const bf16_t* __restrict__ txAll,
    const int* __restrict__ csrSrc, const int* __restrict__ csrPos,
    const int* __restrict__ rowptr, const int* __restrict__ boffP,
    const unsigned* __restrict__ redl, const float* __restrict__ imp, int l,
    const float* __restrict__ accb, const float* __restrict__ h0,
    const float* __restrict__ g, const float* __restrict__ bvec,
    float* __restrict__ h, bf16_t* __restrict__ hb)
{
    __shared__ float smx[4], sinv[4], scoef[4];
    __shared__ int sb[5];
    if (threadIdx.x == 0) {
        float e0 = expf(imp[l * 4 + 0]), e1 = expf(imp[l * 4 + 1]);
        float e2 = expf(imp[l * 4 + 2]), e3 = expf(imp[l * 4 + 3]);
        float den = e0 + e1 + e2 + e3;
        float ews[4] = {e0 / den, e1 / den, e2 / den, e3 / den};
        for (int r = 0; r < 4; r++) {
            smx[r] = fkey_inv(redl[r * 2]);
            sinv[r] = 1.0f / ((const float*)redl)[r * 2 + 1];
            scoef[r] = (1.0f - ALPHA_) * ews[r];
        }
        for (int r = 0; r <= 4; r++) sb[r] = boffP[r];
    }
    __syncthreads();
    int n = blockIdx.x * 4 + (threadIdx.x >> 6);
    if (n >= N_NODES) return;
    int lane = threadIdx.x & 63;
    int c4 = lane * 4;
    float msg[4] = {0, 0, 0, 0};
    int i0 = rowptr[n], i1 = rowptr[n + 1];
    for (int i = i0; i < i1; i++) {
        int src = csrSrc[i];
        int p = csrPos[i];
        int r = 0; while (r < 3 && p >= sb[r + 1]) r++;
        float a = expf(sbuf[p] - smx[r]) * sinv[r] * scoef[r];
        bf16x4_t tv = *(const bf16x4_t*)&txAll[(size_t)src * (R_TYPES * D_) + r * D_ + c4];
        msg[0] += a * (float)tv[0];
        msg[1] += a * (float)tv[1];
        msg[2] += a * (float)tv[2];
        msg[3] += a * (float)tv[3];
    }
    float4 ac = *(const float4*)&accb[(size_t)n * D_ + c4];
    float4 hz = *(const float4*)&h0[(size_t)n * D_ + c4];
    float v[4];
    v[0] = msg[0] + ac.x + ALPHA_ * hz.x;
    v[1] = msg[1] + ac.y + ALPHA_ * hz.y;
    v[2] = msg[2] + ac.z + ALPHA_ * hz.z;
    v[3] = msg[3] + ac.w + ALPHA_ * hz.w;
    float sum = v[0] + v[1] + v[2] + v[3];
    #pragma unroll
    for (int o = 32; o; o >>= 1) sum += __shfl_down(sum, o);
    sum = __shfl(sum, 0);
    float mean = sum * (1.0f / 256.0f);
    float sq = 0.0f;
    #pragma unroll
    for (int j = 0; j < 4; j++) { float d = v[j] - mean; sq += d * d; }
    #pragma unroll
    for (int o = 32; o; o >>= 1) sq += __shfl_down(sq, o);
    sq = __shfl(sq, 0);
    float rstd = rsqrtf(sq * (1.0f / 256.0f) + 1e-5f);
    float4 gg = *(const float4*)&g[c4];
    float4 bb = *(const float4*)&bvec[c4];
    float ga[4] = {gg.x, gg.y, gg.z, gg.w};
    float ba[4] = {bb.x, bb.y, bb.z, bb.w};
    float outv[4];
    bf16_t outb[4];
    #pragma unroll
    for (int j = 0; j < 4; j++) {
        float x = (v[j] - mean) * rstd * ga[j] + ba[j];
        float ge = 0.5f * x * (1.0f + erff(x * 0.7071067811865475f));
        outv[j] = ge;
        outb[j] = (bf16_t)ge;
    }
    *(float4*)&h[(size_t)n * D_ + c4] = *(float4*)outv;
    *(bf16x4_t*)&hb[(size_t)n * D_ + c4] = *(bf16x4_t*)outb;
}

// ---------------- graph mean-pool: segmented register reduction (batch is sorted)
__global__ __launch_bounds__(256) void pool_seg_kernel(
    const float* __restrict__ h, const int* __restrict__ batch,
    float* __restrict__ pooled, float* __restrict__ cntb, int Nn)
{
    int start = blockIdx.x * POOL_CHUNK;
    if (start >= Nn) return;
    int end = start + POOL_CHUNK; if (end > Nn) end = Nn;
    int c = threadIdx.x;
    __shared__ int bseg[POOL_CHUNK];
    if (start + c < Nn) bseg[c] = batch[start + c];
    __syncthreads();
    float acc = 0.0f;
    int cur = bseg[0];
    int segcnt = 0;
    for (int node = start; node < end; node++) {
        int b = bseg[node - start];
        if (b != cur) {
            atomicAdd(&pooled[cur * D_ + c], acc);
            if (c == 0) atomicAdd(&cntb[cur], (float)segcnt);
            acc = 0.0f; segcnt = 0; cur = b;
        }
        acc += h[(size_t)node * D_ + c];
        segcnt++;
    }
    atomicAdd(&pooled[cur * D_ + c], acc);
    if (c == 0) atomicAdd(&cntb[cur], (float)segcnt);
}

// ---------------- graph MLP head (+ add seq logits) -> d_out
__global__ __launch_bounds__(256) void final_mlp_kernel(
    const float* __restrict__ pooled, const float* __restrict__ cntb,
    const float* __restrict__ W1, const float* __restrict__ b1,
    const float* __restrict__ W2, const float* __restrict__ b2,
    const float* __restrict__ W3, const float* __restrict__ b3,
    const float* __restrict__ seqlg, float* __restrict__ out)
{
    int b = blockIdx.x;
    int t = threadIdx.x;
    __shared__ float p[256];
    __shared__ float z1[128];
    __shared__ float z2[64];
    float c = cntb[b]; c = c < 1.0f ? 1.0f : c;
    p[t] = pooled[b * 256 + t] / c;
    __syncthreads();
    if (t < 128) {
        float s = b1[t];
        for (int k = 0; k < 256; k++) s += p[k] * W1[t * 256 + k];
        z1[t] = s > 0.0f ? s : 0.0f;
    }
    __syncthreads();
    if (t < 64) {
        float s = b2[t];
        for (int k = 0; k < 128; k++) s += z1[k] * W2[t * 128 + k];
        z2[t] = s > 0.0f ? s : 0.0f;
    }
    __syncthreads();
    if (t < NC_) {
        float s = b3[t];
        for (int k = 0; k < 64; k++) s += z2[k] * W3[t * 64 + k];
        out[b * NC_ + t] = s + seqlg[b * NC_ + t];
    }
}

// ---------------- GRU input gates for all (dir,b,t); coalesced WihT reads.
__global__ __launch_bounds__(768) void gru_gi_kernel(
    const float* __restrict__ seq, const float* __restrict__ WihT,
    const float* __restrict__ bih, float* __restrict__ gi)
{
    int blk = blockIdx.x;      // 0..127 = dir*64 + b
    int dir = blk >> 6, b = blk & 63;
    __shared__ float xt[T_STEPS * SD_];
    int j = threadIdx.x;
    xt[j] = seq[(size_t)b * T_STEPS * SD_ + j];
    __syncthreads();
    const float* Wt = WihT + (size_t)dir * SD_ * 768;
    float av[T_STEPS] = {};
    for (int k = 0; k < SD_; k++) {
        float w = Wt[(size_t)k * 768 + j];
        #pragma unroll
        for (int t = 0; t < T_STEPS; t++) av[t] += xt[t * SD_ + k] * w;
    }
    float bv = bih[dir * 768 + j];
    for (int t = 0; t < T_STEPS; t++)
        gi[(((size_t)blk) * T_STEPS + t) * 768 + j] = av[t] + bv;
}

// ---------------- GRU recurrent step
__global__ __launch_bounds__(768) void gru_step2(
    const float* __restrict__ gi, const float* __restrict__ WhhT,
    const float* __restrict__ bhh, float* __restrict__ hstate,
    float* __restrict__ outs, int t)
{
    int blk = blockIdx.x;      // 0..127
    int dir = blk >> 6;
    int tin = dir ? (T_STEPS - 1 - t) : t;
    __shared__ float hs[SH_];
    __shared__ float gh[768];
    int j = threadIdx.x;
    if (j < SH_) hs[j] = hstate[(size_t)blk * SH_ + j];
    __syncthreads();
    const float* Wt = WhhT + (size_t)dir * SH_ * 768;
    float a = bhh[dir * 768 + j];
    for (int k = 0; k < SH_; k++)
        a += hs[k] * Wt[(size_t)k * 768 + j];
    gh[j] = a;
    __syncthreads();
    if (j < SH_) {
        size_t gib = (((size_t)blk) * T_STEPS + tin) * 768;
        float r = 1.0f / (1.0f + expf(-(gi[gib + j] + gh[j])));
        float z = 1.0f / (1.0f + expf(-(gi[gib + 256 + j] + gh[256 + j])));
        float n = tanhf(gi[gib + 512 + j] + r * gh[512 + j]);
        float hn = (1.0f - z) * n + z * hs[j];
        hstate[(size_t)blk * SH_ + j] = hn;
        outs[(((size_t)blk) * T_STEPS + tin) * SH_ + j] = hn;
    }
}

// ---------------- seq branch: mean+max pool over T, 3-layer MLP -> seq logits
__global__ __launch_bounds__(256) void seq_mlp_kernel(
    const float* __restrict__ outs, const float* __restrict__ W1, const float* __restrict__ b1,
    const float* __restrict__ W2, const float* __restrict__ b2,
    const float* __restrict__ W3, const float* __restrict__ b3,
    float* __restrict__ seqlg)
{
    int b = blockIdx.x;
    int t = threadIdx.x;
    __shared__ float z[512];
    __shared__ float z1[256];
    __shared__ float z2[128];
    for (int c = t; c < 512; c += 256) {
        int dir = c >> 8, cc = c & 255;
        float mean = 0.0f, mx = -1e30f;
        for (int tt = 0; tt < T_STEPS; tt++) {
            float v = outs[(((size_t)dir * 64 + b) * T_STEPS + tt) * SH_ + cc];
            mean += v; mx = fmaxf(mx, v);
        }
        z[c] = mean * (1.0f / T_STEPS) + mx;
    }
    __syncthreads();
    {
        float s = b1[t];
        for (int k = 0; k < 512; k++) s += z[k] * W1[t * 512 + k];
        z1[t] = s > 0.0f ? s : 0.0f;
    }
    __syncthreads();
    if (t < 128) {
        float s = b2[t];
        for (int k = 0; k < 256; k++) s += z1[k] * W2[t * 256 + k];
        z2[t] = s > 0.0f ? s : 0.0f;
    }
    __syncthreads();
    if (t < NC_) {
        float s = b3[t];
        for (int k = 0; k < 128; k++) s += z2[k] * W3[t * 128 + k];
        seqlg[b * NC_ + t] = s;
    }
}

extern "C" void kernel_launch(void* const* d_in, const int* in_sizes, int n_in,
                              void* d_out, int out_size, void* d_ws, size_t ws_size,
                              hipStream_t stream)
{
    const float* x      = (const float*)d_in[0];
    const int*   ei     = (const int*)d_in[1];
    const int*   et     = (const int*)d_in[2];
    const int*   batch  = (const int*)d_in[3];
    const float* seq    = (const float*)d_in[4];
    const float* proj_W = (const float*)d_in[5];
    const float* proj_b = (const float*)d_in[6];
    const float* Wr     = (const float*)d_in[7];
    const float* Ws     = (const float*)d_in[8];
    const float* bs     = (const float*)d_in[9];
    const float* aW1    = (const float*)d_in[10];
    const float* ab1    = (const float*)d_in[11];
    const float* aW2    = (const float*)d_in[12];
    const float* ab2    = (const float*)d_in[13];
    const float* emb    = (const float*)d_in[14];
    const float* imp    = (const float*)d_in[15];
    const float* ln_g   = (const float*)d_in[16];
    const float* ln_b   = (const float*)d_in[17];
    const float* gmW1   = (const float*)d_in[18];
    const float* gmb1   = (const float*)d_in[19];
    const float* gmW2   = (const float*)d_in[20];
    const float* gmb2   = (const float*)d_in[21];
    const float* gmW3   = (const float*)d_in[22];
    const float* gmb3   = (const float*)d_in[23];
    const float* gWih   = (const float*)d_in[24];
    const float* gWhh   = (const float*)d_in[25];
    const float* gbih   = (const float*)d_in[26];
    const float* gbhh   = (const float*)d_in[27];
    const float* smW1   = (const float*)d_in[28];
    const float* smb1   = (const float*)d_in[29];
    const float* smW2   = (const float*)d_in[30];
    const float* smb2   = (const float*)d_in[31];
    const float* smW3   = (const float*)d_in[32];
    const float* smb3   = (const float*)d_in[33];
    float* out = (float*)d_out;

    // ---- workspace layout (~300 MB)
    char* ws = (char*)d_ws;
    size_t o = 0;
    auto alloc = [&](size_t bytes) -> void* {
        void* p = ws + o;
        o += (bytes + 1023) & ~(size_t)1023;
        return p;
    };
    float*  h0     = (float*)alloc(sizeof(float) * (size_t)N_NODES * D_);
    float*  h      = (float*)alloc(sizeof(float) * (size_t)N_NODES * D_);
    float*  accb   = (float*)alloc(sizeof(float) * (size_t)N_NODES * D_);
    bf16_t* hbb    = (bf16_t*)alloc(sizeof(bf16_t) * (size_t)N_NODES * D_);
    bf16_t* txAll  = (bf16_t*)alloc(sizeof(bf16_t) * (size_t)N_NODES * R_TYPES * D_);
    bf16_t* projWb = (bf16_t*)alloc(sizeof(bf16_t) * D_ * DIN_);
    bf16_t* Wcat   = (bf16_t*)alloc(sizeof(bf16_t) * L_LAYERS * NCAT * D_);
    bf16_t* aW1b   = (bf16_t*)alloc(sizeof(bf16_t) * L_LAYERS * R_TYPES * 128 * 512);
    float*  sbuf   = (float*)alloc(sizeof(float) * E_PAD);
    int*    bsrc   = (int*)alloc(sizeof(int) * E_PAD);
    int*    bdst   = (int*)alloc(sizeof(int) * E_PAD);
    int*    boffP  = (int*)alloc(sizeof(int) * 8);
    int*    cnt    = (int*)alloc(sizeof(int) * 8);
    int*    blockCnt = (int*)alloc(sizeof(int) * NBLK_B * 4);
    int*    basePerBlock = (int*)alloc(sizeof(int) * NBLK_B * 4);
    int*    deg    = (int*)alloc(sizeof(int) * N_NODES);
    int*    rowptr = (int*)alloc(sizeof(int) * (N_NODES + 8));
    int*    cursor = (int*)alloc(sizeof(int) * N_NODES);
    int*    blockSum = (int*)alloc(sizeof(int) * 64);
    int*    blockOff = (int*)alloc(sizeof(int) * 64);
    int*    csrSrc = (int*)alloc(sizeof(int) * E_EDGES);
    int*    csrPos = (int*)alloc(sizeof(int) * E_EDGES);
    unsigned* red  = (unsigned*)alloc(sizeof(unsigned) * 32);
    float*  em     = (float*)alloc(sizeof(float) * 16);
    float*  seqlg  = (float*)alloc(sizeof(float) * BATCH_ * NC_);
    float*  WihT   = (float*)alloc(sizeof(float) * 2 * SD_ * 768);
    float*  WhhT   = (float*)alloc(sizeof(float) * 2 * SH_ * 768);
    float*  gi     = (float*)alloc(sizeof(float) * 2 * BATCH_ * T_STEPS * 768);
    float*  gruH   = (float*)alloc(sizeof(float) * 2 * BATCH_ * SH_);
    float*  gruO   = (float*)alloc(sizeof(float) * 2 * BATCH_ * T_STEPS * SH_);
    float*  pooled = (float*)alloc(sizeof(float) * BATCH_ * D_);
    float*  cntb   = (float*)alloc(sizeof(float) * BATCH_);
    (void)ws_size; (void)in_sizes; (void)n_in; (void)out_size;

    // ---- zero-init (ws is poisoned 0xAA before every timed launch)
    hipMemsetAsync(red, 0, 32 * sizeof(unsigned), stream);
    hipMemsetAsync(gruH, 0, 2 * BATCH_ * SH_ * sizeof(float), stream);
    hipMemsetAsync(pooled, 0, BATCH_ * D_ * sizeof(float), stream);
    hipMemsetAsync(cntb, 0, BATCH_ * sizeof(float), stream);
    hipMemsetAsync(deg, 0, N_NODES * sizeof(int), stream);

    // ---- weight prep
    f2b_kernel<<<64, 256, 0, stream>>>(proj_W, projWb, D_ * DIN_ / 4);
    pack_wcat_kernel<<<512, 256, 0, stream>>>(Ws, Wr, Wcat);
    f2b_kernel<<<256, 256, 0, stream>>>(aW1, aW1b, L_LAYERS * R_TYPES * 128 * 512 / 4);
    transpose2_kernel<<<96, 256, 0, stream>>>(gWih, WihT, 768, SD_);
    transpose2_kernel<<<192, 256, 0, stream>>>(gWhh, WhhT, 768, SH_);

    // ---- edge bucketing by type (deterministic; buckets padded to %64)
    bucket_count2<<<NBLK_B, 256, 0, stream>>>(et, blockCnt);
    bucket_scan<<<1, 64, 0, stream>>>(blockCnt, boffP, cnt, basePerBlock, bsrc, bdst);
    bucket_scatter2<<<NBLK_B, 256, 0, stream>>>(ei, et, basePerBlock, bsrc, bdst);
    embmean_kernel<<<1, 64, 0, stream>>>(emb, em);

    // ---- CSR by dst (for gather-side message aggregation)
    deg_count_kernel<<<1024, 256, 0, stream>>>(bdst, boffP, cnt, deg);
    scan1_kernel<<<SCAN_BLK, 256, 0, stream>>>(deg, rowptr, blockSum);
    scan2_kernel<<<1, 64, 0, stream>>>(blockSum, blockOff);
    scan3_kernel<<<(N_NODES + 255) / 256, 256, 0, stream>>>(rowptr, blockOff, cursor);
    csr_scatter_kernel<<<1024, 256, 0, stream>>>(bsrc, bdst, boffP, cnt, cursor, csrSrc, csrPos);

    // ---- sequence branch
    gru_gi_kernel<<<128, 768, 0, stream>>>(seq, WihT, gbih, gi);
    for (int t = 0; t < T_STEPS; t++)
        gru_step2<<<128, 768, 0, stream>>>(gi, WhhT, gbhh, gruH, gruO, t);
    seq_mlp_kernel<<<BATCH_, 256, 0, stream>>>(gruO, smW1, smb1, smW2, smb2, smW3, smb3, seqlg);

    // ---- graph branch
    const int MB = (N_NODES + 63) / 64;   // 782
    proj_mfma2<<<dim3(MB, 2), 256, 0, stream>>>(x, projWb, proj_b, h0, hbb, N_NODES);
    const int ATTN_BLKS = E_PAD / 64;     // 5004
    for (int l = 0; l < L_LAYERS; l++) {
        // [accb | txAll] = hbb @ Wcat[l].T  (N=1280, dual output)
        linear_dual_mfma2<<<dim3(MB, NCAT / 128), 256, 0, stream>>>(
            hbb, Wcat + (size_t)l * NCAT * D_, bs + l * D_, accb, txAll, N_NODES);
        // attention scores for all 4 types
        attn_mfma<<<ATTN_BLKS, 256, 0, stream>>>(hbb, bsrc, bdst, boffP, cnt, l,
                                                 aW1b, ab1, aW2, ab2, em, sbuf);
        bucket_max_kernel<<<dim3(256, 4), 256, 0, stream>>>(sbuf, boffP, red + l * 8);
        bucket_sum_kernel<<<dim3(256, 4), 256, 0, stream>>>(sbuf, boffP, red + l * 8);
        // fused: gather messages per dst + residual + LN + GELU (no atomics)
        msg_ln_gelu_kernel<<<(N_NODES + 3) / 4, 256, 0, stream>>>(
            sbuf, txAll, csrSrc, csrPos, rowptr, boffP, red + l * 8, imp, l,
            accb, h0, ln_g + l * D_, ln_b + l * D_, h, hbb);
    }

    // ---- pooling + heads
    pool_seg_kernel<<<(N_NODES + POOL_CHUNK - 1) / POOL_CHUNK, 256, 0, stream>>>(h, batch, pooled, cntb, N_NODES);
    final_mlp_kernel<<<BATCH_, 256, 0, stream>>>(pooled, cntb, gmW1, gmb1, gmW2, gmb2, gmW3, gmb3, seqlg, out);
}

// Round 9
// 1572.105 us; speedup vs baseline: 1.0796x; 1.0796x over previous
//
#include <hip/hip_runtime.h>
#include <math.h>

#define N_NODES 50000
#define E_EDGES 320000
#define DIN_    768
#define D_      256
#define R_TYPES 4
#define L_LAYERS 3
#define BATCH_  64
#define T_STEPS 6
#define SD_     128
#define SH_     256
#define NC_     14
#define ALPHA_  0.15f
#define NBLK_B  1250
#define POOL_CHUNK 256
#define E_PAD   (E_EDGES + 256)
#define SCAN_BLK 49
#define NCAT    (D_ + R_TYPES * D_)   // 1280

typedef __bf16 bf16_t;
typedef bf16_t bf16x8_t __attribute__((ext_vector_type(8)));
typedef bf16_t bf16x4_t __attribute__((ext_vector_type(4)));
typedef float  f32x4_t  __attribute__((ext_vector_type(4)));

__device__ __forceinline__ f32x4_t mfma16(bf16x8_t a, bf16x8_t b, f32x4_t c) {
    return __builtin_amdgcn_mfma_f32_16x16x32_bf16(a, b, c, 0, 0, 0);
}

// ---------------- fp32 -> bf16 conversion (vector4, n % 4 == 0)
__global__ void f2b_kernel(const float* __restrict__ src, bf16_t* __restrict__ dst, int n4)
{
    for (int i = blockIdx.x * blockDim.x + threadIdx.x; i < n4; i += gridDim.x * blockDim.x) {
        float4 v = ((const float4*)src)[i];
        bf16_t o[4] = {(bf16_t)v.x, (bf16_t)v.y, (bf16_t)v.z, (bf16_t)v.w};
        *(ulong1*)&dst[i * 4] = *(ulong1*)o;
    }
}

// ---------------- pack Wcat[l] = [Ws[l] | Wr[l][0..3]] as bf16
__global__ void pack_wcat_kernel(const float* __restrict__ Ws, const float* __restrict__ Wr,
                                 bf16_t* __restrict__ Wcat)
{
    int total = L_LAYERS * NCAT * D_;
    for (int i = blockIdx.x * blockDim.x + threadIdx.x; i < total; i += gridDim.x * blockDim.x) {
        int l = i / (NCAT * D_);
        int rem = i - l * NCAT * D_;
        int row = rem / D_, k = rem - row * D_;
        float v = (row < D_) ? Ws[((size_t)l * D_ + row) * D_ + k]
                             : Wr[((size_t)l * R_TYPES * D_ + (row - D_)) * D_ + k];
        Wcat[i] = (bf16_t)v;
    }
}

// ---------------- [2][R][C] -> [2][C][R] transpose (small weights)
__global__ void transpose2_kernel(const float* __restrict__ in, float* __restrict__ out, int R, int C)
{
    int total = 2 * R * C;
    for (int i = blockIdx.x * blockDim.x + threadIdx.x; i < total; i += gridDim.x * blockDim.x) {
        int dir = i / (R * C);
        int rem = i - dir * R * C;
        int r = rem / C, c = rem - r * C;
        out[dir * R * C + c * R + r] = in[i];
    }
}

// ---------------- proj GEMM v3: bf16 A (pre-converted), 64x64 tile, grid (MB, 4).
// xb (77 MB) fits L3 so the repeated n-passes mostly hit L3.
__global__ __launch_bounds__(256) void proj_mfma3(
    const bf16_t* __restrict__ A, const bf16_t* __restrict__ W,
    const float* __restrict__ bias, float* __restrict__ outf,
    bf16_t* __restrict__ outb, int M)
{
    __shared__ bf16_t As[64][44];
    __shared__ bf16_t Bs[64][44];
    const int m0 = blockIdx.x * 64;
    const int n0 = blockIdx.y * 64;
    const int tid = threadIdx.x;
    const int wave = tid >> 6, lane = tid & 63;
    const int wy = wave >> 1, wx = wave & 1;
    const int q = lane >> 4, c = lane & 15;
    const int srow = tid >> 2, skq = tid & 3;

    f32x4_t acc[2][2] = {};
    for (int k0 = 0; k0 < DIN_; k0 += 32) {
        {
            int m = m0 + srow;
            bf16x8_t av = {};
            if (m < M) av = *(const bf16x8_t*)&A[(size_t)m * DIN_ + k0 + skq * 8];
            *(bf16x8_t*)&As[srow][skq * 8] = av;
            *(bf16x8_t*)&Bs[srow][skq * 8] = *(const bf16x8_t*)&W[(size_t)(n0 + srow) * DIN_ + k0 + skq * 8];
        }
        __syncthreads();
        bf16x8_t af[2], bfv[2];
        #pragma unroll
        for (int mt = 0; mt < 2; mt++) af[mt] = *(const bf16x8_t*)&As[wy * 32 + mt * 16 + c][q * 8];
        #pragma unroll
        for (int nt = 0; nt < 2; nt++) bfv[nt] = *(const bf16x8_t*)&Bs[wx * 32 + nt * 16 + c][q * 8];
        #pragma unroll
        for (int mt = 0; mt < 2; mt++)
            #pragma unroll
            for (int nt = 0; nt < 2; nt++)
                acc[mt][nt] = mfma16(af[mt], bfv[nt], acc[mt][nt]);
        __syncthreads();
    }
    #pragma unroll
    for (int mt = 0; mt < 2; mt++) {
        #pragma unroll
        for (int nt = 0; nt < 2; nt++) {
            int n = n0 + wx * 32 + nt * 16 + c;
            float bv = bias[n];
            #pragma unroll
            for (int j = 0; j < 4; j++) {
                int m = m0 + wy * 32 + mt * 16 + q * 4 + j;
                if (m < M) {
                    float v = acc[mt][nt][j] + bv;
                    outf[(size_t)m * D_ + n] = v;
                    outb[(size_t)m * D_ + n] = (bf16_t)v;
                }
            }
        }
    }
}

// ---------------- dual GEMM (R7 64x64 version): [accb | txAll] = hbb @ Wcat[l].T
__global__ __launch_bounds__(256) void linear_dual_mfma(
    const bf16_t* __restrict__ A, const bf16_t* __restrict__ W,
    const float* __restrict__ bias, float* __restrict__ outf,
    bf16_t* __restrict__ outb, int M)
{
    __shared__ bf16_t As[64][44];
    __shared__ bf16_t Bs[64][44];
    const int m0 = blockIdx.x * 64;
    const int n0 = blockIdx.y * 64;
    const int tid = threadIdx.x;
    const int wave = tid >> 6, lane = tid & 63;
    const int wy = wave >> 1, wx = wave & 1;
    const int q = lane >> 4, c = lane & 15;
    const int srow = tid >> 2, skq = tid & 3;

    f32x4_t acc[2][2] = {};
    for (int k0 = 0; k0 < D_; k0 += 32) {
        {
            int m = m0 + srow;
            bf16x8_t av = {};
            if (m < M) av = *(const bf16x8_t*)&A[(size_t)m * D_ + k0 + skq * 8];
            *(bf16x8_t*)&As[srow][skq * 8] = av;
            *(bf16x8_t*)&Bs[srow][skq * 8] = *(const bf16x8_t*)&W[(size_t)(n0 + srow) * D_ + k0 + skq * 8];
        }
        __syncthreads();
        bf16x8_t af[2], bfv[2];
        #pragma unroll
        for (int mt = 0; mt < 2; mt++) af[mt] = *(const bf16x8_t*)&As[wy * 32 + mt * 16 + c][q * 8];
        #pragma unroll
        for (int nt = 0; nt < 2; nt++) bfv[nt] = *(const bf16x8_t*)&Bs[wx * 32 + nt * 16 + c][q * 8];
        #pragma unroll
        for (int mt = 0; mt < 2; mt++)
            #pragma unroll
            for (int nt = 0; nt < 2; nt++)
                acc[mt][nt] = mfma16(af[mt], bfv[nt], acc[mt][nt]);
        __syncthreads();
    }
    #pragma unroll
    for (int mt = 0; mt < 2; mt++) {
        #pragma unroll
        for (int nt = 0; nt < 2; nt++) {
            int n = n0 + wx * 32 + nt * 16 + c;
            float bv = (n < D_) ? bias[n] : 0.0f;
            #pragma unroll
            for (int j = 0; j < 4; j++) {
                int m = m0 + wy * 32 + mt * 16 + q * 4 + j;
                if (m < M) {
                    float v = acc[mt][nt][j] + bv;
                    if (n < D_) outf[(size_t)m * D_ + n] = v;
                    else        outb[(size_t)m * (R_TYPES * D_) + (n - D_)] = (bf16_t)v;
                }
            }
        }
    }
}

// ---------------- edge bucketing by type: deterministic 3-phase, zero global atomics
__global__ __launch_bounds__(256) void bucket_count2(const int* __restrict__ et,
                                                     int* __restrict__ blockCnt)
{
    int b = blockIdx.x, tid = threadIdx.x;
    int r = et[b * 256 + tid];
    int lane = tid & 63, wv = tid >> 6;
    __shared__ int wcnt[4][4];
    #pragma unroll
    for (int t = 0; t < 4; t++) {
        unsigned long long m = __ballot(r == t);
        if (lane == 0) wcnt[wv][t] = __popcll(m);
    }
    __syncthreads();
    if (tid < 4)
        blockCnt[b * 4 + tid] = wcnt[0][tid] + wcnt[1][tid] + wcnt[2][tid] + wcnt[3][tid];
}

__global__ void bucket_scan(const int* __restrict__ blockCnt, int* __restrict__ boffP,
                            int* __restrict__ cnt, int* __restrict__ basePerBlock,
                            int* __restrict__ bsrc, int* __restrict__ bdst)
{
    __shared__ int tot[4];
    int t = threadIdx.x;
    if (t < 4) {
        int s = 0;
        for (int b = 0; b < NBLK_B; b++) s += blockCnt[b * 4 + t];
        tot[t] = s;
    }
    __syncthreads();
    if (t == 0) {
        int o = 0;
        for (int r = 0; r < 4; r++) {
            boffP[r] = o; cnt[r] = tot[r];
            o += (tot[r] + 63) & ~63;
        }
        boffP[4] = o;
    }
    __syncthreads();
    if (t < 4) {
        int run = boffP[t];
        for (int b = 0; b < NBLK_B; b++) { basePerBlock[b * 4 + t] = run; run += blockCnt[b * 4 + t]; }
    }
    __syncthreads();
    for (int r = 0; r < 4; r++) {
        int s = boffP[r] + cnt[r], e = boffP[r + 1];
        for (int i = s + t; i < e; i += 64) { bsrc[i] = 0; bdst[i] = 0; }
    }
}

__global__ __launch_bounds__(256) void bucket_scatter2(
    const int* __restrict__ ei, const int* __restrict__ et,
    const int* __restrict__ basePerBlock, int* __restrict__ bsrc, int* __restrict__ bdst)
{
    int b = blockIdx.x, tid = threadIdx.x;
    int e = b * 256 + tid;
    int r = et[e];
    int lane = tid & 63, wv = tid >> 6;
    __shared__ int wcnt[4][4];
    int myrank = 0;
    unsigned long long ltmask = (1ull << lane) - 1ull;
    #pragma unroll
    for (int t = 0; t < 4; t++) {
        unsigned long long m = __ballot(r == t);
        if (r == t) myrank = __popcll(m & ltmask);
        if (lane == 0) wcnt[wv][t] = __popcll(m);
    }
    __syncthreads();
    int wbase = 0;
    for (int w = 0; w < wv; w++) wbase += wcnt[w][r];
    int pos = basePerBlock[b * 4 + r] + wbase + myrank;
    bsrc[pos] = ei[e];
    bdst[pos] = ei[E_EDGES + e];
}

__global__ void embmean_kernel(const float* __restrict__ emb, float* __restrict__ em)
{
    int lr = threadIdx.x;
    if (lr < L_LAYERS * R_TYPES) {
        float s = 0.0f;
        for (int k = 0; k < 64; k++) s += emb[lr * 64 + k];
        em[lr] = s / 64.0f;
    }
}

// ---------------- CSR-by-dst build
__global__ __launch_bounds__(256) void deg_count_kernel(
    const int* __restrict__ bdst, const int* __restrict__ boffP, const int* __restrict__ cnt,
    int* __restrict__ deg)
{
    __shared__ int sb[5], sc[4];
    if (threadIdx.x < 5) sb[threadIdx.x] = boffP[threadIdx.x];
    if (threadIdx.x < 4) sc[threadIdx.x] = cnt[threadIdx.x];
    __syncthreads();
    int total = sb[4];
    for (int p = blockIdx.x * blockDim.x + threadIdx.x; p < total; p += gridDim.x * blockDim.x) {
        int r = 0; while (r < 3 && p >= sb[r + 1]) r++;
        if (p - sb[r] < sc[r]) atomicAdd(&deg[bdst[p]], 1);
    }
}

__global__ __launch_bounds__(256) void scan1_kernel(const int* __restrict__ deg,
                                                    int* __restrict__ rowptr, int* __restrict__ blockSum)
{
    __shared__ int sdata[256];
    int b = blockIdx.x, t = threadIdx.x;
    int idx0 = b * 1024 + t * 4;
    int d[4];
    #pragma unroll
    for (int j = 0; j < 4; j++) d[j] = (idx0 + j < N_NODES) ? deg[idx0 + j] : 0;
    int tsum = d[0] + d[1] + d[2] + d[3];
    sdata[t] = tsum;
    __syncthreads();
    for (int off = 1; off < 256; off <<= 1) {
        int v = (t >= off) ? sdata[t - off] : 0;
        __syncthreads();
        sdata[t] += v;
        __syncthreads();
    }
    int ex = sdata[t] - tsum;
    int acc = ex;
    #pragma unroll
    for (int j = 0; j < 4; j++) {
        if (idx0 + j < N_NODES) rowptr[idx0 + j] = acc;
        acc += d[j];
    }
    if (t == 255) blockSum[b] = sdata[255];
}

__global__ void scan2_kernel(const int* __restrict__ blockSum, int* __restrict__ blockOff)
{
    if (threadIdx.x == 0) {
        int o = 0;
        for (int b = 0; b < SCAN_BLK; b++) { blockOff[b] = o; o += blockSum[b]; }
    }
}

__global__ __launch_bounds__(256) void scan3_kernel(int* __restrict__ rowptr,
                                                    const int* __restrict__ blockOff,
                                                    int* __restrict__ cursor)
{
    int idx = blockIdx.x * blockDim.x + threadIdx.x;
    if (idx < N_NODES) {
        int v = rowptr[idx] + blockOff[idx >> 10];
        rowptr[idx] = v; cursor[idx] = v;
    }
    if (idx == 0) rowptr[N_NODES] = E_EDGES;
}

__global__ __launch_bounds__(256) void csr_scatter_kernel(
    const int* __restrict__ bsrc, const int* __restrict__ bdst,
    const int* __restrict__ boffP, const int* __restrict__ cnt,
    int* __restrict__ cursor, int* __restrict__ csrSrc, int* __restrict__ csrPos)
{
    __shared__ int sb[5], sc[4];
    if (threadIdx.x < 5) sb[threadIdx.x] = boffP[threadIdx.x];
    if (threadIdx.x < 4) sc[threadIdx.x] = cnt[threadIdx.x];
    __syncthreads();
    int total = sb[4];
    for (int p = blockIdx.x * blockDim.x + threadIdx.x; p < total; p += gridDim.x * blockDim.x) {
        int r = 0; while (r < 3 && p >= sb[r + 1]) r++;
        if (p - sb[r] < sc[r]) {
            int pos = atomicAdd(&cursor[bdst[p]], 1);
            csrSrc[pos] = bsrc[p];
            csrPos[pos] = p;
        }
    }
}

// ---------------- MFMA attention score, ALL types in one launch (padded buckets).
__global__ __launch_bounds__(256) void attn_mfma(
    const bf16_t* __restrict__ hb, const int* __restrict__ bsrc, const int* __restrict__ bdst,
    const int* __restrict__ boffP, const int* __restrict__ cnt, int l,
    const bf16_t* __restrict__ W1base, const float* __restrict__ b1base,
    const float* __restrict__ W2base, const float* __restrict__ b2base,
    const float* __restrict__ em, float* __restrict__ sbuf)
{
    const int p0 = blockIdx.x * 64;
    if (p0 >= boffP[4]) return;
    int r = 0;
    while (r < 3 && p0 >= boffP[r + 1]) r++;
    const int lr = l * R_TYPES + r;
    const int base = boffP[r];
    const int cnt_r = cnt[r];
    const bf16_t* W1 = W1base + (size_t)lr * 128 * 512;
    const float*  b1 = b1base + lr * 128;
    const float*  W2 = W2base + lr * 128;

    __shared__ int nd_d[64], nd_s[64];
    __shared__ bf16_t Acat[64][44];
    __shared__ bf16_t Bs[128][44];
    const int tid = threadIdx.x;
    if (tid < 64) nd_d[tid] = bdst[p0 + tid];
    else if (tid < 128) nd_s[tid - 64] = bsrc[p0 + tid - 64];
    __syncthreads();
    const int wave = tid >> 6, lane = tid & 63;
    const int q = lane >> 4, c = lane & 15;
    const int srow = tid >> 2, skq = tid & 3;

    f32x4_t acc[8] = {};
    for (int ks = 0; ks < 16; ks++) {
        {
            int node = (ks < 8) ? nd_d[srow] : nd_s[srow];
            int koffm = (ks & 7) * 32 + skq * 8;
            *(bf16x8_t*)&Acat[srow][skq * 8] = *(const bf16x8_t*)&hb[(size_t)node * D_ + koffm];
            #pragma unroll
            for (int s = 0; s < 2; s++) {
                int slot = tid + s * 256;
                int nrow = slot >> 2, nkq = slot & 3;
                *(bf16x8_t*)&Bs[nrow][nkq * 8] = *(const bf16x8_t*)&W1[(size_t)nrow * 512 + ks * 32 + nkq * 8];
            }
        }
        __syncthreads();
        bf16x8_t af = *(const bf16x8_t*)&Acat[wave * 16 + c][q * 8];
        #pragma unroll
        for (int nt = 0; nt < 8; nt++) {
            bf16x8_t bfv = *(const bf16x8_t*)&Bs[nt * 16 + c][q * 8];
            acc[nt] = mfma16(af, bfv, acc[nt]);
        }
        __syncthreads();
    }
    float part[4] = {0, 0, 0, 0};
    #pragma unroll
    for (int nt = 0; nt < 8; nt++) {
        int n = nt * 16 + c;
        float b1v = b1[n], w2v = W2[n];
        #pragma unroll
        for (int j = 0; j < 4; j++) {
            float v = acc[nt][j] + b1v;
            v = v > 0.0f ? v : 0.0f;
            part[j] += v * w2v;
        }
    }
    #pragma unroll
    for (int j = 0; j < 4; j++) {
        #pragma unroll
        for (int mask = 1; mask <= 8; mask <<= 1)
            part[j] += __shfl_xor(part[j], mask);
    }
    if (c == 0) {
        float b2v = b2base[lr], emv = em[lr];
        #pragma unroll
        for (int j = 0; j < 4; j++) {
            int p = p0 + wave * 16 + q * 4 + j;
            bool valid = (p - base) < cnt_r;
            float sv = part[j] + b2v;
            sv = sv > 0.0f ? sv : 0.2f * sv;   // leaky_relu(0.2)
            sbuf[p] = valid ? (sv + emv) : -1e30f;
        }
    }
}

// ---------------- masked-softmax helpers
__device__ __forceinline__ unsigned fkey(float f) {
    unsigned u = __float_as_uint(f);
    return (u & 0x80000000u) ? ~u : (u | 0x80000000u);
}
__device__ __forceinline__ float fkey_inv(unsigned k) {
    unsigned u = (k & 0x80000000u) ? (k ^ 0x80000000u) : ~k;
    return __uint_as_float(u);
}

// grid = (256, 4): blockIdx.y = type. redl = red + l*8.
__global__ void bucket_max_kernel(const float* __restrict__ sbuf, const int* __restrict__ boffP,
                                  unsigned* __restrict__ redl)
{
    int r = blockIdx.y;
    int lo = boffP[r], hi = boffP[r + 1];
    float m = -1e30f;
    for (int i = lo + blockIdx.x * blockDim.x + threadIdx.x; i < hi; i += gridDim.x * blockDim.x)
        m = fmaxf(m, sbuf[i]);
    for (int o = 32; o; o >>= 1) m = fmaxf(m, __shfl_down(m, o));
    __shared__ float wm[4];
    int lane = threadIdx.x & 63, wv = threadIdx.x >> 6;
    if (lane == 0) wm[wv] = m;
    __syncthreads();
    if (threadIdx.x == 0) {
        float b = fmaxf(fmaxf(wm[0], wm[1]), fmaxf(wm[2], wm[3]));
        atomicMax(&redl[r * 2], fkey(b));
    }
}

__global__ void bucket_sum_kernel(const float* __restrict__ sbuf, const int* __restrict__ boffP,
                                  unsigned* __restrict__ redl)
{
    int r = blockIdx.y;
    int lo = boffP[r], hi = boffP[r + 1];
    float mxf = fkey_inv(redl[r * 2]);
    float s = 0.0f;
    for (int i = lo + blockIdx.x * blockDim.x + threadIdx.x; i < hi; i += gridDim.x * blockDim.x)
        s += expf(sbuf[i] - mxf);
    for (int o = 32; o; o >>= 1) s += __shfl_down(s, o);
    __shared__ float wm[4];
    int lane = threadIdx.x & 63, wv = threadIdx.x >> 6;
    if (lane == 0) wm[wv] = s;
    __syncthreads();
    if (threadIdx.x == 0) atomicAdd((float*)&redl[r * 2 + 1], wm[0] + wm[1] + wm[2] + wm[3]);
}

// ---------------- FUSED message-gather + residual + LayerNorm + GELU (bf16 out only).
__global__ __launch_bounds__(256) void msg_ln_gelu_kernel(
    const float* __restrict__ sbuf, const bf16_t* __restrict__ txAll,
    const int* __restrict__ csrSrc, const int* __restrict__ csrPos,
    const int* __restrict__ rowptr, const int* __restrict__ boffP,
    const unsigned* __restrict__ redl, const float* __restrict__ imp, int l,
    const float* __restrict__ accb, const float* __restrict__ h0,
    const float* __restrict__ g, const float* __restrict__ bvec,
    bf16_t* __restrict__ hb)
{
    __shared__ float smx[4], sinv[4], scoef[4];
    __shared__ int sb[5];
    if (threadIdx.x == 0) {
        float e0 = expf(imp[l * 4 + 0]), e1 = expf(imp[l * 4 + 1]);
        float e2 = expf(imp[l * 4 + 2]), e3 = expf(imp[l * 4 + 3]);
        float den = e0 + e1 + e2 + e3;
        float ews[4] = {e0 / den, e1 / den, e2 / den, e3 / den};
        for (int r = 0; r < 4; r++) {
            smx[r] = fkey_inv(redl[r * 2]);
            sinv[r] = 1.0f / ((const float*)redl)[r * 2 + 1];
            scoef[r] = (1.0f - ALPHA_) * ews[r];
        }
        for (int r = 0; r <= 4; r++) sb[r] = boffP[r];
    }
    __syncthreads();
    int n = blockIdx.x * 4 + (threadIdx.x >> 6);
    if (n >= N_NODES) return;
    int lane = threadIdx.x & 63;
    int c4 = lane * 4;
    float msg[4] = {0, 0, 0, 0};
    int i0 = rowptr[n], i1 = rowptr[n + 1];
    for (int i = i0; i < i1; i++) {
        int src = csrSrc[i];
        int p = csrPos[i];
        int r = 0; while (r < 3 && p >= sb[r + 1]) r++;
        float a = expf(sbuf[p] - smx[r]) * sinv[r] * scoef[r];
        bf16x4_t tv = *(const bf16x4_t*)&txAll[(size_t)src * (R_TYPES * D_) + r * D_ + c4];
        msg[0] += a * (float)tv[0];
        msg[1] += a * (float)tv[1];
        msg[2] += a * (float)tv[2];
        msg[3] += a * (float)tv[3];
    }
    float4 ac = *(const float4*)&accb[(size_t)n * D_ + c4];
    float4 hz = *(const float4*)&h0[(size_t)n * D_ + c4];
    float v[4];
    v[0] = msg[0] + ac.x + ALPHA_ * hz.x;
    v[1] = msg[1] + ac.y + ALPHA_ * hz.y;
    v[2] = msg[2] + ac.z + ALPHA_ * hz.z;
    v[3] = msg[3] + ac.w + ALPHA_ * hz.w;
    float sum = v[0] + v[1] + v[2] + v[3];
    #pragma unroll
    for (int o = 32; o; o >>= 1) sum += __shfl_down(sum, o);
    sum = __shfl(sum, 0);
    float mean = sum * (1.0f / 256.0f);
    float sq = 0.0f;
    #pragma unroll
    for (int j = 0; j < 4; j++) { float d = v[j] - mean; sq += d * d; }
    #pragma unroll
    for (int o = 32; o; o >>= 1) sq += __shfl_down(sq, o);
    sq = __shfl(sq, 0);
    float rstd = rsqrtf(sq * (1.0f / 256.0f) + 1e-5f);
    float4 gg = *(const float4*)&g[c4];
    float4 bb = *(const float4*)&bvec[c4];
    float ga[4] = {gg.x, gg.y, gg.z, gg.w};
    float ba[4] = {bb.x, bb.y, bb.z, bb.w};
    bf16_t outb[4];
    #pragma unroll
    for (int j = 0; j < 4; j++) {
        float x = (v[j] - mean) * rstd * ga[j] + ba[j];
        float ge = 0.5f * x * (1.0f + erff(x * 0.7071067811865475f));
        outb[j] = (bf16_t)ge;
    }
    *(bf16x4_t*)&hb[(size_t)n * D_ + c4] = *(bf16x4_t*)outb;
}

// ---------------- graph mean-pool over bf16 h (batch is sorted)
__global__ __launch_bounds__(256) void pool_seg_kernel(
    const bf16_t* __restrict__ hb, const int* __restrict__ batch,
    float* __restrict__ pooled, float* __restrict__ cntb, int Nn)
{
    int start = blockIdx.x * POOL_CHUNK;
    if (start >= Nn) return;
    int end = start + POOL_CHUNK; if (end > Nn) end = Nn;
    int c = threadIdx.x;
    __shared__ int bseg[POOL_CHUNK];
    if (start + c < Nn) bseg[c] = batch[start + c];
    __syncthreads();
    float acc = 0.0f;
    int cur = bseg[0];
    int segcnt = 0;
    for (int node = start; node < end; node++) {
        int b = bseg[node - start];
        if (b != cur) {
            atomicAdd(&pooled[cur * D_ + c], acc);
            if (c == 0) atomicAdd(&cntb[cur], (float)segcnt);
            acc = 0.0f; segcnt = 0; cur = b;
        }
        acc += (float)hb[(size_t)node * D_ + c];
        segcnt++;
    }
    atomicAdd(&pooled[cur * D_ + c], acc);
    if (c == 0) atomicAdd(&cntb[cur], (float)segcnt);
}

// ---------------- graph MLP head (+ add seq logits) -> d_out
__global__ __launch_bounds__(256) void final_mlp_kernel(
    const float* __restrict__ pooled, const float* __restrict__ cntb,
    const float* __restrict__ W1, const float* __restrict__ b1,
    const float* __restrict__ W2, const float* __restrict__ b2,
    const float* __restrict__ W3, const float* __restrict__ b3,
    const float* __restrict__ seqlg, float* __restrict__ out)
{
    int b = blockIdx.x;
    int t = threadIdx.x;
    __shared__ float p[256];
    __shared__ float z1[128];
    __shared__ float z2[64];
    float c = cntb[b]; c = c < 1.0f ? 1.0f : c;
    p[t] = pooled[b * 256 + t] / c;
    __syncthreads();
    if (t < 128) {
        float s = b1[t];
        for (int k = 0; k < 256; k++) s += p[k] * W1[t * 256 + k];
        z1[t] = s > 0.0f ? s : 0.0f;
    }
    __syncthreads();
    if (t < 64) {
        float s = b2[t];
        for (int k = 0; k < 128; k++) s += z1[k] * W2[t * 128 + k];
        z2[t] = s > 0.0f ? s : 0.0f;
    }
    __syncthreads();
    if (t < NC_) {
        float s = b3[t];
        for (int k = 0; k < 64; k++) s += z2[k] * W3[t * 64 + k];
        out[b * NC_ + t] = s + seqlg[b * NC_ + t];
    }
}

// ---------------- single-kernel bidirectional GRU: one block per (dir,b),
// all 6 timesteps internal (gi in registers, h in LDS). No global h state.
__global__ __launch_bounds__(768) void gru_full(
    const float* __restrict__ seq, const float* __restrict__ WihT,
    const float* __restrict__ bih, const float* __restrict__ WhhT,
    const float* __restrict__ bhh, float* __restrict__ outs)
{
    int blk = blockIdx.x;      // 0..127 = dir*64 + b
    int dir = blk >> 6, b = blk & 63;
    __shared__ float xt[T_STEPS * SD_];
    __shared__ float hs[SH_];
    __shared__ float gh[768];
    __shared__ float gg[768];
    int j = threadIdx.x;
    xt[j] = seq[(size_t)b * T_STEPS * SD_ + j];
    if (j < SH_) hs[j] = 0.0f;
    __syncthreads();
    const float* Wti = WihT + (size_t)dir * SD_ * 768;
    float av[T_STEPS] = {};
    for (int k = 0; k < SD_; k++) {
        float w = Wti[(size_t)k * 768 + j];
        #pragma unroll
        for (int t = 0; t < T_STEPS; t++) av[t] += xt[t * SD_ + k] * w;
    }
    float bihv = bih[dir * 768 + j];
    float bhhv = bhh[dir * 768 + j];
    const float* Wth = WhhT + (size_t)dir * SH_ * 768;
    for (int t = 0; t < T_STEPS; t++) {
        int tin = dir ? (T_STEPS - 1 - t) : t;
        float a = bhhv;
        for (int k = 0; k < SH_; k++)
            a += hs[k] * Wth[(size_t)k * 768 + j];
        gh[j] = a;
        gg[j] = av[tin] + bihv;
        __syncthreads();
        if (j < SH_) {
            float r = 1.0f / (1.0f + expf(-(gg[j] + gh[j])));
            float z = 1.0f / (1.0f + expf(-(gg[256 + j] + gh[256 + j])));
            float n = tanhf(gg[512 + j] + r * gh[512 + j]);
            float hn = (1.0f - z) * n + z * hs[j];
            hs[j] = hn;
            outs[(((size_t)blk) * T_STEPS + tin) * SH_ + j] = hn;
        }
        __syncthreads();
    }
}

// ---------------- seq branch: mean+max pool over T, 3-layer MLP -> seq logits
__global__ __launch_bounds__(256) void seq_mlp_kernel(
    const float* __restrict__ outs, const float* __restrict__ W1, const float* __restrict__ b1,
    const float* __restrict__ W2, const float* __restrict__ b2,
    const float* __restrict__ W3, const float* __restrict__ b3,
    float* __restrict__ seqlg)
{
    int b = blockIdx.x;
    int t = threadIdx.x;
    __shared__ float z[512];
    __shared__ float z1[256];
    __shared__ float z2[128];
    for (int c = t; c < 512; c += 256) {
        int dir = c >> 8, cc = c & 255;
        float mean = 0.0f, mx = -1e30f;
        for (int tt = 0; tt < T_STEPS; tt++) {
            float v = outs[(((size_t)dir * 64 + b) * T_STEPS + tt) * SH_ + cc];
            mean += v; mx = fmaxf(mx, v);
        }
        z[c] = mean * (1.0f / T_STEPS) + mx;
    }
    __syncthreads();
    {
        float s = b1[t];
        for (int k = 0; k < 512; k++) s += z[k] * W1[t * 512 + k];
        z1[t] = s > 0.0f ? s : 0.0f;
    }
    __syncthreads();
    if (t < 128) {
        float s = b2[t];
        for (int k = 0; k < 256; k++) s += z1[k] * W2[t * 256 + k];
        z2[t] = s > 0.0f ? s : 0.0f;
    }
    __syncthreads();
    if (t < NC_) {
        float s = b3[t];
        for (int k = 0; k < 128; k++) s += z2[k] * W3[t * 128 + k];
        seqlg[b * NC_ + t] = s;
    }
}

extern "C" void kernel_launch(void* const* d_in, const int* in_sizes, int n_in,
                              void* d_out, int out_size, void* d_ws, size_t ws_size,
                              hipStream_t stream)
{
    const float* x      = (const float*)d_in[0];
    const int*   ei     = (const int*)d_in[1];
    const int*   et     = (const int*)d_in[2];
    const int*   batch  = (const int*)d_in[3];
    const float* seq    = (const float*)d_in[4];
    const float* proj_W = (const float*)d_in[5];
    const float* proj_b = (const float*)d_in[6];
    const float* Wr     = (const float*)d_in[7];
    const float* Ws     = (const float*)d_in[8];
    const float* bs     = (const float*)d_in[9];
    const float* aW1    = (const float*)d_in[10];
    const float* ab1    = (const float*)d_in[11];
    const float* aW2    = (const float*)d_in[12];
    const float* ab2    = (const float*)d_in[13];
    const float* emb    = (const float*)d_in[14];
    const float* imp    = (const float*)d_in[15];
    const float* ln_g   = (const float*)d_in[16];
    const float* ln_b   = (const float*)d_in[17];
    const float* gmW1   = (const float*)d_in[18];
    const float* gmb1   = (const float*)d_in[19];
    const float* gmW2   = (const float*)d_in[20];
    const float* gmb2   = (const float*)d_in[21];
    const float* gmW3   = (const float*)d_in[22];
    const float* gmb3   = (const float*)d_in[23];
    const float* gWih   = (const float*)d_in[24];
    const float* gWhh   = (const float*)d_in[25];
    const float* gbih   = (const float*)d_in[26];
    const float* gbhh   = (const float*)d_in[27];
    const float* smW1   = (const float*)d_in[28];
    const float* smb1   = (const float*)d_in[29];
    const float* smW2   = (const float*)d_in[30];
    const float* smb2   = (const float*)d_in[31];
    const float* smW3   = (const float*)d_in[32];
    const float* smb3   = (const float*)d_in[33];
    float* out = (float*)d_out;

    // ---- workspace layout (~330 MB)
    char* ws = (char*)d_ws;
    size_t o = 0;
    auto alloc = [&](size_t bytes) -> void* {
        void* p = ws + o;
        o += (bytes + 1023) & ~(size_t)1023;
        return p;
    };
    float*  h0     = (float*)alloc(sizeof(float) * (size_t)N_NODES * D_);
    float*  accb   = (float*)alloc(sizeof(float) * (size_t)N_NODES * D_);
    bf16_t* hbb    = (bf16_t*)alloc(sizeof(bf16_t) * (size_t)N_NODES * D_);
    bf16_t* xb     = (bf16_t*)alloc(sizeof(bf16_t) * (size_t)N_NODES * DIN_);
    bf16_t* txAll  = (bf16_t*)alloc(sizeof(bf16_t) * (size_t)N_NODES * R_TYPES * D_);
    bf16_t* projWb = (bf16_t*)alloc(sizeof(bf16_t) * D_ * DIN_);
    bf16_t* Wcat   = (bf16_t*)alloc(sizeof(bf16_t) * L_LAYERS * NCAT * D_);
    bf16_t* aW1b   = (bf16_t*)alloc(sizeof(bf16_t) * L_LAYERS * R_TYPES * 128 * 512);
    float*  sbuf   = (float*)alloc(sizeof(float) * E_PAD);
    int*    bsrc   = (int*)alloc(sizeof(int) * E_PAD);
    int*    bdst   = (int*)alloc(sizeof(int) * E_PAD);
    int*    boffP  = (int*)alloc(sizeof(int) * 8);
    int*    cnt    = (int*)alloc(sizeof(int) * 8);
    int*    blockCnt = (int*)alloc(sizeof(int) * NBLK_B * 4);
    int*    basePerBlock = (int*)alloc(sizeof(int) * NBLK_B * 4);
    int*    deg    = (int*)alloc(sizeof(int) * N_NODES);
    int*    rowptr = (int*)alloc(sizeof(int) * (N_NODES + 8));
    int*    cursor = (int*)alloc(sizeof(int) * N_NODES);
    int*    blockSum = (int*)alloc(sizeof(int) * 64);
    int*    blockOff = (int*)alloc(sizeof(int) * 64);
    int*    csrSrc = (int*)alloc(sizeof(int) * E_EDGES);
    int*    csrPos = (int*)alloc(sizeof(int) * E_EDGES);
    unsigned* red  = (unsigned*)alloc(sizeof(unsigned) * 32);
    float*  em     = (float*)alloc(sizeof(float) * 16);
    float*  seqlg  = (float*)alloc(sizeof(float) * BATCH_ * NC_);
    float*  WihT   = (float*)alloc(sizeof(float) * 2 * SD_ * 768);
    float*  WhhT   = (float*)alloc(sizeof(float) * 2 * SH_ * 768);
    float*  gruO   = (float*)alloc(sizeof(float) * 2 * BATCH_ * T_STEPS * SH_);
    float*  pooled = (float*)alloc(sizeof(float) * BATCH_ * D_);
    float*  cntb   = (float*)alloc(sizeof(float) * BATCH_);
    (void)ws_size; (void)in_sizes; (void)n_in; (void)out_size;

    // ---- zero-init (ws is poisoned 0xAA before every timed launch)
    hipMemsetAsync(red, 0, 32 * sizeof(unsigned), stream);
    hipMemsetAsync(pooled, 0, BATCH_ * D_ * sizeof(float), stream);
    hipMemsetAsync(cntb, 0, BATCH_ * sizeof(float), stream);
    hipMemsetAsync(deg, 0, N_NODES * sizeof(int), stream);

    // ---- weight prep + x conversion
    f2b_kernel<<<2048, 256, 0, stream>>>(x, xb, N_NODES * DIN_ / 4);
    f2b_kernel<<<64, 256, 0, stream>>>(proj_W, projWb, D_ * DIN_ / 4);
    pack_wcat_kernel<<<512, 256, 0, stream>>>(Ws, Wr, Wcat);
    f2b_kernel<<<256, 256, 0, stream>>>(aW1, aW1b, L_LAYERS * R_TYPES * 128 * 512 / 4);
    transpose2_kernel<<<96, 256, 0, stream>>>(gWih, WihT, 768, SD_);
    transpose2_kernel<<<192, 256, 0, stream>>>(gWhh, WhhT, 768, SH_);

    // ---- edge bucketing by type (deterministic; buckets padded to %64)
    bucket_count2<<<NBLK_B, 256, 0, stream>>>(et, blockCnt);
    bucket_scan<<<1, 64, 0, stream>>>(blockCnt, boffP, cnt, basePerBlock, bsrc, bdst);
    bucket_scatter2<<<NBLK_B, 256, 0, stream>>>(ei, et, basePerBlock, bsrc, bdst);
    embmean_kernel<<<1, 64, 0, stream>>>(emb, em);

    // ---- CSR by dst
    deg_count_kernel<<<1024, 256, 0, stream>>>(bdst, boffP, cnt, deg);
    scan1_kernel<<<SCAN_BLK, 256, 0, stream>>>(deg, rowptr, blockSum);
    scan2_kernel<<<1, 64, 0, stream>>>(blockSum, blockOff);
    scan3_kernel<<<(N_NODES + 255) / 256, 256, 0, stream>>>(rowptr, blockOff, cursor);
    csr_scatter_kernel<<<1024, 256, 0, stream>>>(bsrc, bdst, boffP, cnt, cursor, csrSrc, csrPos);

    // ---- sequence branch (single-kernel GRU)
    gru_full<<<128, 768, 0, stream>>>(seq, WihT, gbih, WhhT, gbhh, gruO);
    seq_mlp_kernel<<<BATCH_, 256, 0, stream>>>(gruO, smW1, smb1, smW2, smb2, smW3, smb3, seqlg);

    // ---- graph branch
    const int MB = (N_NODES + 63) / 64;   // 782
    proj_mfma3<<<dim3(MB, D_ / 64), 256, 0, stream>>>(xb, projWb, proj_b, h0, hbb, N_NODES);
    const int ATTN_BLKS = E_PAD / 64;     // 5004
    for (int l = 0; l < L_LAYERS; l++) {
        linear_dual_mfma<<<dim3(MB, NCAT / 64), 256, 0, stream>>>(
            hbb, Wcat + (size_t)l * NCAT * D_, bs + l * D_, accb, txAll, N_NODES);
        attn_mfma<<<ATTN_BLKS, 256, 0, stream>>>(hbb, bsrc, bdst, boffP, cnt, l,
                                                 aW1b, ab1, aW2, ab2, em, sbuf);
        bucket_max_kernel<<<dim3(256, 4), 256, 0, stream>>>(sbuf, boffP, red + l * 8);
        bucket_sum_kernel<<<dim3(256, 4), 256, 0, stream>>>(sbuf, boffP, red + l * 8);
        msg_ln_gelu_kernel<<<(N_NODES + 3) / 4, 256, 0, stream>>>(
            sbuf, txAll, csrSrc, csrPos, rowptr, boffP, red + l * 8, imp, l,
            accb, h0, ln_g + l * D_, ln_b + l * D_, hbb);
    }

    // ---- pooling + heads
    pool_seg_kernel<<<(N_NODES + POOL_CHUNK - 1) / POOL_CHUNK, 256, 0, stream>>>(hbb, batch, pooled, cntb, N_NODES);
    final_mlp_kernel<<<BATCH_, 256, 0, stream>>>(pooled, cntb, gmW1, gmb1, gmW2, gmb2, gmW3, gmb3, seqlg, out);
}